// Round 1
// baseline (125.954 us; speedup 1.0000x reference)
//
#include <hip/hip_runtime.h>
#include <math.h>

#define NPOS  2048
#define NANCH 4096          // pos + neg
#define CIN   1280
#define HID   128
#define A_    9
#define W_    28
#define HW_   784           // 28*28
#define AHW   7056          // 9*784
#define FB    (CIN*HW_)     // floats per batch image = 1,003,520

__device__ __forceinline__ float sigmoidf_(float x) {
    return 1.0f / (1.0f + __expf(-x));
}

// ---------------------------------------------------------------------------
// K1: fused gather + GEMM1 partials.
// grid = (64 pos-tiles, ksel k-splits), block = 256.
// Each block: 64 anchors x 128 outputs over a K-chunk of `kchunk` channels.
// Writes Hp[ks][pos][o] partial sums (no bias/activation yet).
// ---------------------------------------------------------------------------
__global__ __launch_bounds__(256) void k_gemm1(
    const float* __restrict__ F, const int* __restrict__ posi,
    const int* __restrict__ negi, const float* __restrict__ W1,
    float* __restrict__ Hp, int kchunk)
{
    __shared__ int   baseb[64];
    __shared__ float Gl[16][68];     // [kk][pos]  (pad 68: 2-way max)
    __shared__ float Wl[16][132];    // [kk][o]    (pad 132: 16B-aligned rows)

    const int t  = threadIdx.x;
    const int pt = blockIdx.x;
    const int kbase0 = blockIdx.y * kchunk;

    if (t < 64) {
        int g    = pt * 64 + t;
        int aidx = (g < NPOS) ? posi[g] : negi[g - NPOS];
        int b    = aidx / AHW;
        int rem  = aidx - b * AHW;
        int hw   = rem % HW_;
        int hh   = hw / W_;
        int ww   = hw - hh * W_;
        baseb[t] = b * FB + hh * W_ + ww;
    }

    float acc[4][8];
#pragma unroll
    for (int i = 0; i < 4; ++i)
#pragma unroll
        for (int j = 0; j < 8; ++j) acc[i][j] = 0.0f;

    const int tx = t & 15;     // pos micro (4 each)
    const int ty = t >> 4;     // o micro (8 each)
    const int nsub = kchunk >> 4;

    for (int s = 0; s < nsub; ++s) {
        const int kb = kbase0 + (s << 4);
        __syncthreads();
        // stage W1 chunk -> Wl[kk][o], coalesced 16-float runs
        {
            const int kk = t & 15;
            const int o0 = t >> 4;
#pragma unroll
            for (int pass = 0; pass < 8; ++pass) {
                int o = pass * 16 + o0;
                Wl[kk][o] = W1[o * CIN + kb + kk];
            }
        }
        // stage gathered features -> Gl[kk][p]
        {
            const int p  = t & 63;
            const int k0 = t >> 6;         // 0..3
            const int base = baseb[p];
#pragma unroll
            for (int pass = 0; pass < 4; ++pass) {
                int kk = pass * 4 + k0;
                Gl[kk][p] = F[base + (kb + kk) * HW_];
            }
        }
        __syncthreads();
#pragma unroll
        for (int kk = 0; kk < 16; ++kk) {
            const float4 g4 = *(const float4*)&Gl[kk][tx << 2];
            const float4 wA = *(const float4*)&Wl[kk][ty << 3];
            const float4 wB = *(const float4*)&Wl[kk][(ty << 3) + 4];
            const float gg[4]  = {g4.x, g4.y, g4.z, g4.w};
            const float wwv[8] = {wA.x, wA.y, wA.z, wA.w, wB.x, wB.y, wB.z, wB.w};
#pragma unroll
            for (int i = 0; i < 4; ++i)
#pragma unroll
                for (int j = 0; j < 8; ++j)
                    acc[i][j] = fmaf(gg[i], wwv[j], acc[i][j]);
        }
    }

    // write partials
    const int posg = (pt << 6) + (tx << 2);
    float* dst = Hp + ((size_t)blockIdx.y * NANCH + posg) * HID + (ty << 3);
#pragma unroll
    for (int i = 0; i < 4; ++i) {
        float4 s0 = {acc[i][0], acc[i][1], acc[i][2], acc[i][3]};
        float4 s1 = {acc[i][4], acc[i][5], acc[i][6], acc[i][7]};
        *(float4*)&dst[(size_t)i * HID]     = s0;
        *(float4*)&dst[(size_t)i * HID + 4] = s1;
    }
}

// ---------------------------------------------------------------------------
// K2: reduce k-split partials + bias + leaky_relu -> H[4096][128]
// ---------------------------------------------------------------------------
__global__ __launch_bounds__(256) void k_reduce_bias(
    const float* __restrict__ Hp, const float* __restrict__ b1,
    float* __restrict__ Hout, int ksel)
{
    const int j = blockIdx.x * 256 + threadIdx.x;   // < NANCH*HID
    const int o = j & (HID - 1);
    float s = b1[o];
    for (int ks = 0; ks < ksel; ++ks) s += Hp[(size_t)ks * (NANCH * HID) + j];
    Hout[j] = (s > 0.0f) ? s : 0.01f * s;
}

// ---------------------------------------------------------------------------
// K3: wave-per-anchor: layer-2 (25 or 1 rows) + IoU/argmax + losses
// grid = NANCH/4, block = 256 (4 waves).
// ---------------------------------------------------------------------------
__global__ __launch_bounds__(256) void k_loss(
    const float* __restrict__ H, const float* __restrict__ W2,
    const float* __restrict__ b2, const int* __restrict__ posi,
    const int* __restrict__ negi, const float* __restrict__ bboxes,
    const float* __restrict__ anc, float* __restrict__ contrib)
{
    const int wid  = threadIdx.x >> 6;
    const int lane = threadIdx.x & 63;
    const int g    = blockIdx.x * 4 + wid;

    const int aidx = (g < NPOS) ? posi[g] : negi[g - NPOS];
    const int b   = aidx / AHW;
    const int rem = aidx - b * AHW;
    const int a   = rem / HW_;
    const int hw  = rem - a * HW_;
    const int hh  = hw / W_;
    const int ww  = hw - hh * W_;

    const float2 h2 = *(const float2*)&H[(size_t)g * HID + 2 * lane];

    if (g < NPOS) {
        float out[25];
#pragma unroll
        for (int j = 0; j < 25; ++j) {
            const int row = (j < 5) ? (5 * a + j) : (40 + j);
            const float2 w = *(const float2*)&W2[(size_t)row * HID + 2 * lane];
            float v = fmaf(w.x, h2.x, w.y * h2.y);
#pragma unroll
            for (int off = 1; off < 64; off <<= 1) v += __shfl_xor(v, off, 64);
            out[j] = v + b2[row];
        }

        // anchor box
        const float wa = anc[2 * a], ha = anc[2 * a + 1];
        const float cx = ww + 0.5f, cy = hh + 0.5f;
        const float ax1 = cx - 0.5f * wa, ay1 = cy - 0.5f * ha;
        const float ax2 = cx + 0.5f * wa, ay2 = cy + 0.5f * ha;
        const float areap = wa * ha;

        // IoU over 40 gt boxes (lane j computes box j), argmax w/ first-max tie-break
        float v; int vi = lane;
        if (lane < 40) {
            const float* bb = &bboxes[(size_t)(b * 40 + lane) * 5];
            const float bx1 = bb[0], by1 = bb[1], bx2 = bb[2], by2 = bb[3];
            const float areab = (bx2 - bx1) * (by2 - by1);
            const float ix1 = fmaxf(ax1, bx1), iy1 = fmaxf(ay1, by1);
            const float ix2 = fminf(ax2, bx2), iy2 = fminf(ay2, by2);
            const float inter = fmaxf(ix2 - ix1, 0.0f) * fmaxf(iy2 - iy1, 0.0f);
            v = inter / (areap + areab - inter);
        } else {
            v = -1.0f;
        }
#pragma unroll
        for (int off = 1; off < 64; off <<= 1) {
            const float ov = __shfl_xor(v, off, 64);
            const int   oi = __shfl_xor(vi, off, 64);
            if (ov > v || (ov == v && oi < vi)) { v = ov; vi = oi; }
        }
        const int m = vi;

        const float* gt = &bboxes[(size_t)(b * 40 + m) * 5];
        const float gx1 = gt[0], gy1 = gt[1], gx2 = gt[2], gy2 = gt[3];
        const int   gcls = (int)gt[4];
        const float xb = 0.5f * (gx1 + gx2), yb = 0.5f * (gy1 + gy2);
        const float wb = gx2 - gx1, hb = gy2 - gy1;
        const float go0 = xb - cx, go1 = yb - cy;
        const float go2 = __logf(wb / wa), go3 = __logf(hb / ha);

        const float o0 = sigmoidf_(out[1]) - 0.5f;
        const float o1 = sigmoidf_(out[2]) - 0.5f;
        const float o2 = out[3], o3 = out[4];
        const float reg = (o0 - go0) * (o0 - go0) + (o1 - go1) * (o1 - go1) +
                          (o2 - go2) * (o2 - go2) + (o3 - go3) * (o3 - go3);

        const float conf = sigmoidf_(out[0]);
        const float conft = (conf - 1.0f) * (conf - 1.0f);

        float mx = out[5];
#pragma unroll
        for (int c = 1; c < 20; ++c) mx = fmaxf(mx, out[5 + c]);
        float se = 0.0f;
#pragma unroll
        for (int c = 0; c < 20; ++c) se += __expf(out[5 + c] - mx);
        float lgt = 0.0f;
#pragma unroll
        for (int c = 0; c < 20; ++c) if (c == gcls) lgt = out[5 + c];
        const float clst = -(lgt - mx - __logf(se));

        if (lane == 0)
            contrib[g] = conft * (1.0f / 4096.0f) + reg * (1.0f / 2048.0f) +
                         clst * (1.0f / 2048.0f);
    } else {
        const int row = 5 * a;
        const float2 w = *(const float2*)&W2[(size_t)row * HID + 2 * lane];
        float v = fmaf(w.x, h2.x, w.y * h2.y);
#pragma unroll
        for (int off = 1; off < 64; off <<= 1) v += __shfl_xor(v, off, 64);
        const float conf = sigmoidf_(v + b2[row]);
        if (lane == 0) contrib[g] = conf * conf * (1.0f / 4096.0f);
    }
}

// ---------------------------------------------------------------------------
// K4: final reduction of 4096 contributions -> d_out[0]
// ---------------------------------------------------------------------------
__global__ __launch_bounds__(256) void k_final(const float* __restrict__ contrib,
                                               float* __restrict__ out)
{
    __shared__ float red[256];
    const int t = threadIdx.x;
    float s = 0.0f;
    for (int i = t; i < NANCH; i += 256) s += contrib[i];
    red[t] = s;
    __syncthreads();
    for (int st = 128; st > 0; st >>= 1) {
        if (t < st) red[t] += red[t + st];
        __syncthreads();
    }
    if (t == 0) out[0] = red[0];
}

extern "C" void kernel_launch(void* const* d_in, const int* in_sizes, int n_in,
                              void* d_out, int out_size, void* d_ws, size_t ws_size,
                              hipStream_t stream)
{
    const float* F      = (const float*)d_in[0];
    const float* bboxes = (const float*)d_in[1];
    const int*   posi   = (const int*)d_in[2];
    const int*   negi   = (const int*)d_in[3];
    const float* W1     = (const float*)d_in[4];
    const float* b1     = (const float*)d_in[5];
    const float* W2     = (const float*)d_in[6];
    const float* b2     = (const float*)d_in[7];
    const float* anc    = (const float*)d_in[8];
    float* out = (float*)d_out;

    // choose K-split by workspace budget (chunk = 1280/ksel must be /16)
    const int opts[8] = {20, 16, 10, 8, 5, 4, 2, 1};
    int ksel = 1;
    for (int i = 0; i < 8; ++i) {
        size_t need = ((size_t)opts[i] * NANCH * HID + (size_t)NANCH * HID + NANCH)
                      * sizeof(float);
        if (need <= ws_size) { ksel = opts[i]; break; }
    }

    float* Hp      = (float*)d_ws;
    float* Hbuf    = Hp + (size_t)ksel * NANCH * HID;
    float* contrib = Hbuf + (size_t)NANCH * HID;

    k_gemm1<<<dim3(64, ksel), 256, 0, stream>>>(F, posi, negi, W1, Hp, CIN / ksel);
    k_reduce_bias<<<(NANCH * HID) / 256, 256, 0, stream>>>(Hp, b1, Hbuf, ksel);
    k_loss<<<NANCH / 4, 256, 0, stream>>>(Hbuf, W2, b2, posi, negi, bboxes, anc,
                                          contrib);
    k_final<<<1, 256, 0, stream>>>(contrib, out);
    (void)in_sizes; (void)n_in; (void)out_size;
}